// Round 1
// baseline (201.161 us; speedup 1.0000x reference)
//
#include <hip/hip_runtime.h>

#define EPSN   1e-8f
#define MARGIN 0.2f
#define ALPHA  0.1f
#define BETA   1.05f
#define DIM    512
#define NCLS   16

typedef __attribute__((ext_vector_type(8))) short short8;
typedef __attribute__((ext_vector_type(4))) float f32x4;

__device__ __forceinline__ unsigned short f2bf(float f) {
    unsigned u = __float_as_uint(f);
    return (unsigned short)((u + 0x7FFFu + ((u >> 16) & 1u)) >> 16);  // RNE
}
__device__ __forceinline__ short8 pack8(float4 x0, float4 x1) {
    short8 r;
    r[0] = (short)f2bf(x0.x); r[1] = (short)f2bf(x0.y);
    r[2] = (short)f2bf(x0.z); r[3] = (short)f2bf(x0.w);
    r[4] = (short)f2bf(x1.x); r[5] = (short)f2bf(x1.y);
    r[6] = (short)f2bf(x1.z); r[7] = (short)f2bf(x1.w);
    return r;
}

// ---------------- Kernel 1: triplet loss partial sum -> scal[0] ----------------
__global__ __launch_bounds__(256) void k_triplet(const float* __restrict__ A,
                                                 const float* __restrict__ P,
                                                 const float* __restrict__ Q,
                                                 float* __restrict__ scal, int N) {
    __shared__ float red[4];
    int t = threadIdx.x, lane = t & 63, wid = t >> 6;
    int gw = blockIdx.x * 4 + wid, nw = gridDim.x * 4;
    float tri = 0.f;
    for (int row = gw; row < N; row += nw) {
        size_t base = (size_t)row * DIM;
        const float4* a = (const float4*)(A + base) + lane;
        const float4* p = (const float4*)(P + base) + lane;
        const float4* q = (const float4*)(Q + base) + lane;
        float4 a0 = a[0], a1 = a[64];
        float4 p0 = p[0], p1 = p[64];
        float4 q0 = q[0], q1 = q[64];
        float sa = 0, sp = 0, sn = 0, dap = 0, dan = 0;
        sa  = fmaf(a0.x,a0.x, fmaf(a0.y,a0.y, fmaf(a0.z,a0.z, fmaf(a0.w,a0.w,
              fmaf(a1.x,a1.x, fmaf(a1.y,a1.y, fmaf(a1.z,a1.z, a1.w*a1.w)))))));
        sp  = fmaf(p0.x,p0.x, fmaf(p0.y,p0.y, fmaf(p0.z,p0.z, fmaf(p0.w,p0.w,
              fmaf(p1.x,p1.x, fmaf(p1.y,p1.y, fmaf(p1.z,p1.z, p1.w*p1.w)))))));
        sn  = fmaf(q0.x,q0.x, fmaf(q0.y,q0.y, fmaf(q0.z,q0.z, fmaf(q0.w,q0.w,
              fmaf(q1.x,q1.x, fmaf(q1.y,q1.y, fmaf(q1.z,q1.z, q1.w*q1.w)))))));
        dap = fmaf(a0.x,p0.x, fmaf(a0.y,p0.y, fmaf(a0.z,p0.z, fmaf(a0.w,p0.w,
              fmaf(a1.x,p1.x, fmaf(a1.y,p1.y, fmaf(a1.z,p1.z, a1.w*p1.w)))))));
        dan = fmaf(a0.x,q0.x, fmaf(a0.y,q0.y, fmaf(a0.z,q0.z, fmaf(a0.w,q0.w,
              fmaf(a1.x,q1.x, fmaf(a1.y,q1.y, fmaf(a1.z,q1.z, a1.w*q1.w)))))));
#pragma unroll
        for (int o = 32; o > 0; o >>= 1) {
            sa  += __shfl_xor(sa,  o);
            sp  += __shfl_xor(sp,  o);
            sn  += __shfl_xor(sn,  o);
            dap += __shfl_xor(dap, o);
            dan += __shfl_xor(dan, o);
        }
        float na = fmaxf(sqrtf(sa), EPSN);
        float np = fmaxf(sqrtf(sp), EPSN);
        float nn = fmaxf(sqrtf(sn), EPSN);
        float posd = 1.f - dap / (na * np);
        float negd = 1.f - dan / (na * nn);
        tri += fmaxf(posd - negd + MARGIN, 0.f);
    }
    if (lane == 0) red[wid] = tri;   // identical across lanes of a wave
    __syncthreads();
    if (t == 0) atomicAdd(&scal[0], red[0] + red[1] + red[2] + red[3]);
}

// ---------------- Kernel 2: per-class sums + counts ----------------
__global__ __launch_bounds__(256) void k_segsum(const float* __restrict__ E,
                                                const int* __restrict__ L,
                                                float* __restrict__ sums,
                                                int* __restrict__ counts, int N) {
    __shared__ float acc[NCLS * DIM];
    __shared__ int cl[NCLS];
    int t = threadIdx.x;
    for (int i = t; i < NCLS * DIM; i += 256) acc[i] = 0.f;
    if (t < NCLS) cl[t] = 0;
    __syncthreads();
    for (int r = blockIdx.x * 4; r < N; r += gridDim.x * 4) {
        int l0 = L[r], l1 = L[r + 1], l2 = L[r + 2], l3 = L[r + 3];
        float2 v0 = *((const float2*)(E + (size_t)r       * DIM) + t);
        float2 v1 = *((const float2*)(E + (size_t)(r + 1) * DIM) + t);
        float2 v2 = *((const float2*)(E + (size_t)(r + 2) * DIM) + t);
        float2 v3 = *((const float2*)(E + (size_t)(r + 3) * DIM) + t);
        float2* p;
        p = (float2*)&acc[l0 * DIM] + t; p->x += v0.x; p->y += v0.y;
        p = (float2*)&acc[l1 * DIM] + t; p->x += v1.x; p->y += v1.y;
        p = (float2*)&acc[l2 * DIM] + t; p->x += v2.x; p->y += v2.y;
        p = (float2*)&acc[l3 * DIM] + t; p->x += v3.x; p->y += v3.y;
        if (t == 0) { cl[l0]++; cl[l1]++; cl[l2]++; cl[l3]++; }
    }
    __syncthreads();
    for (int i = t; i < NCLS * DIM; i += 256) atomicAdd(&sums[i], acc[i]);
    if (t < NCLS) atomicAdd(&counts[t], cl[t]);
}

// ---------------- Kernel 3 (tiny): centroids, normalize, pair matrix, cnt, n_terms ----------------
__global__ __launch_bounds__(256) void k_centroid(const float* __restrict__ sums,
                                                  const int* __restrict__ counts,
                                                  float* __restrict__ ncn_g,
                                                  float* __restrict__ pairf_g,
                                                  float* __restrict__ cntf_g,
                                                  float* __restrict__ scal) {
    __shared__ float ncn[NCLS * DIM];
    __shared__ float red[256];
    int t = threadIdx.x;
    for (int c = 0; c < NCLS; ++c) {
        float inv = 1.f / fmaxf((float)counts[c], 1.f);
        float s0 = sums[c * DIM + t] * inv;
        float s1 = sums[c * DIM + 256 + t] * inv;
        ncn[c * DIM + t] = s0;
        ncn[c * DIM + 256 + t] = s1;
        red[t] = s0 * s0 + s1 * s1;
        __syncthreads();
        for (int o = 128; o > 0; o >>= 1) { if (t < o) red[t] += red[t + o]; __syncthreads(); }
        float rs = 1.f / fmaxf(sqrtf(red[0]), EPSN);
        ncn[c * DIM + t] *= rs;
        ncn[c * DIM + 256 + t] *= rs;
        __syncthreads();
    }
    for (int i = t; i < NCLS * DIM; i += 256) ncn_g[i] = ncn[i];
    __syncthreads();
    // pair matrix in full fp32 (binary decisions are sensitive -> no bf16 here)
    int i = t >> 4, j = t & 15;
    float dot = 0.f;
    for (int d = 0; d < DIM; ++d) dot += ncn[i * DIM + d] * ncn[j * DIM + d];
    float cd = 1.f - dot;
    float pf = (cd <= BETA && i != j && counts[i] > 0 && counts[j] > 0) ? 1.f : 0.f;
    pairf_g[t] = pf;
    red[t] = pf;
    __syncthreads();
    if (t < NCLS) {
        float s = 0.f;
        for (int k = 0; k < NCLS; ++k) s += red[t * 16 + k];
        cntf_g[t] = s;
    }
    __syncthreads();
    if (t == 0) {
        float nt = 0.f;
        for (int k = 0; k < NCLS; ++k) nt += cntf_g[k] * (float)counts[k];
        scal[3] = nt;
        scal[4] = 1.f / fmaxf(nt, 1.f);
    }
}

// ---------------- Kernel 4: D = ê·ncn^T via bf16 MFMA; intra/inter partials ----------------
__global__ __launch_bounds__(256) void k_atn(const float* __restrict__ E,
                                             const int* __restrict__ L,
                                             const float* __restrict__ ncn,
                                             const float* __restrict__ pairf,
                                             const float* __restrict__ cntf,
                                             float* __restrict__ scal, int N) {
    __shared__ float pr[NCLS * NCLS];
    __shared__ float cf[NCLS];
    __shared__ float red[8];
    int t = threadIdx.x, lane = t & 63, wid = t >> 6;
    pr[t] = pairf[t];
    if (t < NCLS) cf[t] = cntf[t];
    __syncthreads();

    int col = lane & 15;      // A-row within tile == B-col (class)
    int kg = lane >> 4;       // k-group 0..3
    short8 bfr[16];           // B fragments for all 16 K-steps, held in VGPRs
#pragma unroll
    for (int s = 0; s < 16; ++s) {
        const float4* q = (const float4*)(ncn + col * DIM + s * 32 + kg * 8);
        bfr[s] = pack8(q[0], q[1]);
    }

    float inter = 0.f, intra = 0.f;
    int gw = blockIdx.x * 4 + wid, nw = gridDim.x * 4;
    int ntile = N >> 4;
    for (int tile = gw; tile < ntile; tile += nw) {
        int rowb = tile << 4;
        const float* ar = E + (size_t)(rowb + col) * DIM + kg * 8;
        f32x4 acc = {0.f, 0.f, 0.f, 0.f};
        float ss = 0.f;
#pragma unroll
        for (int s = 0; s < 16; ++s) {
            float4 x0 = *(const float4*)(ar + s * 32);
            float4 x1 = *(const float4*)(ar + s * 32 + 4);
            ss = fmaf(x0.x, x0.x, ss); ss = fmaf(x0.y, x0.y, ss);
            ss = fmaf(x0.z, x0.z, ss); ss = fmaf(x0.w, x0.w, ss);
            ss = fmaf(x1.x, x1.x, ss); ss = fmaf(x1.y, x1.y, ss);
            ss = fmaf(x1.z, x1.z, ss); ss = fmaf(x1.w, x1.w, ss);
            acc = __builtin_amdgcn_mfma_f32_16x16x32_bf16(pack8(x0, x1), bfr[s], acc, 0, 0, 0);
        }
        // lane holds sumsq partial of row (lane&15) over its k-quarter; combine quarters
        ss += __shfl_xor(ss, 16);
        ss += __shfl_xor(ss, 32);
#pragma unroll
        for (int reg = 0; reg < 4; ++reg) {
            int row = kg * 4 + reg;            // C/D: col=lane&15, row=(lane>>4)*4+reg
            float s2 = __shfl(ss, row);        // lane 'row' holds sumsq of row 'row'
            float rinv = 1.f / fmaxf(sqrtf(s2), EPSN);
            float d = 1.f - acc[reg] * rinv;
            int lab = L[rowb + row];
            inter += pr[lab * 16 + col] * fmaxf(BETA - d, 0.f);
            if (col == lab) intra += cf[lab] * fmaxf(d - ALPHA, 0.f);
        }
    }
#pragma unroll
    for (int o = 32; o > 0; o >>= 1) {
        inter += __shfl_xor(inter, o);
        intra += __shfl_xor(intra, o);
    }
    if (lane == 0) { red[wid] = intra; red[4 + wid] = inter; }
    __syncthreads();
    if (t == 0) {
        atomicAdd(&scal[1], red[0] + red[1] + red[2] + red[3]);
        atomicAdd(&scal[2], red[4] + red[5] + red[6] + red[7]);
    }
}

// ---------------- Kernel 5: combine ----------------
__global__ void k_final(const float* __restrict__ scal, float* __restrict__ out, float invN) {
    float tri = scal[0] * invN;
    float atn = (scal[3] > 0.f) ? (scal[1] + scal[2]) * scal[4] : 0.f;
    out[0] = tri + atn;
}

extern "C" void kernel_launch(void* const* d_in, const int* in_sizes, int n_in,
                              void* d_out, int out_size, void* d_ws, size_t ws_size,
                              hipStream_t stream) {
    const float* A = (const float*)d_in[0];
    const float* P = (const float*)d_in[1];
    const float* Q = (const float*)d_in[2];
    const float* E = (const float*)d_in[3];
    const int*   L = (const int*)d_in[4];
    int N = in_sizes[0] / DIM;

    char* ws = (char*)d_ws;
    float* sums   = (float*)ws;             // 8192 f32 = 32768 B
    int*   counts = (int*)(ws + 32768);     // 16 i32
    float* scal   = (float*)(ws + 32832);   // [0]=tri [1]=intra [2]=inter [3]=n_terms [4]=1/max(n,1)
    float* ncn    = (float*)(ws + 36864);   // 8192 f32 normalized centroids
    float* pairf  = (float*)(ws + 69632);   // 256 f32
    float* cntf   = (float*)(ws + 70656);   // 16 f32

    hipMemsetAsync(d_ws, 0, 36864, stream); // zero accumulators every call

    k_triplet <<<2048, 256, 0, stream>>>(A, P, Q, scal, N);
    k_segsum  <<<512,  256, 0, stream>>>(E, L, sums, counts, N);
    k_centroid<<<1,    256, 0, stream>>>(sums, counts, ncn, pairf, cntf, scal);
    k_atn     <<<512,  256, 0, stream>>>(E, L, ncn, pairf, cntf, scal, N);
    k_final   <<<1, 1, 0, stream>>>(scal, (float*)d_out, 1.f / (float)N);
}